// Round 1
// baseline (1201.271 us; speedup 1.0000x reference)
//
#include <hip/hip_runtime.h>
#include <hip/hip_bf16.h>

// Sizes
#define BB 64
#define LL 25
#define DD 128
#define BL 1600           // B*L
#define POI_N 10000
#define CAT_N 400

// ---------------------------------------------------------------------------
// Embedding gather: x = ue[user]+pe[poi]+te[tod]+de[dow]; xc = uec+ce+tec+dec
// Also initializes the min/max atomic slots (kernel boundary orders it before
// the minmax kernel).
// ---------------------------------------------------------------------------
__global__ __launch_bounds__(256) void embed_kernel(
    const int* __restrict__ user, const int* __restrict__ poi, const int* __restrict__ cat,
    const int* __restrict__ tod, const int* __restrict__ dow,
    const float* __restrict__ ue, const float* __restrict__ pe, const float* __restrict__ ce,
    const float* __restrict__ te, const float* __restrict__ de,
    const float* __restrict__ uec, const float* __restrict__ tec, const float* __restrict__ dec,
    float* __restrict__ x, float* __restrict__ xc, unsigned* __restrict__ mm)
{
    int idx = blockIdx.x * 256 + threadIdx.x;           // 0 .. 204799 exactly
    if (idx == 0) { mm[0] = 0u; mm[1] = 0x7f7fffffu; }  // gmax=0.0f, gmin=FLT_MAX (all D>=0)
    int bl = idx >> 7, d = idx & 127;
    int u = user[bl], p = poi[bl], c = cat[bl], td = tod[bl], dw = dow[bl];
    x[idx]  = ue[u * DD + d] + pe[p * DD + d] + te[td * DD + d] + de[dw * DD + d];
    xc[idx] = uec[u * DD + d] + ce[c * DD + d] + tec[td * DD + d] + dec[dw * DD + d];
}

// ---------------------------------------------------------------------------
// Global max/min over the 1600 gathered distance rows (duplicates don't change
// max/min). One block per (b,l) row; float-as-uint atomics (values >= 0).
// ---------------------------------------------------------------------------
__global__ __launch_bounds__(256) void minmax_kernel(
    const int* __restrict__ poi, const float* __restrict__ Dm, unsigned* __restrict__ mm)
{
    int bl = blockIdx.x;
    const float4* r = (const float4*)(Dm + (size_t)poi[bl] * POI_N);
    float mx = -1e30f, mn = 1e30f;
    for (int i = threadIdx.x; i < POI_N / 4; i += 256) {
        float4 v4 = r[i];
        mx = fmaxf(mx, fmaxf(fmaxf(v4.x, v4.y), fmaxf(v4.z, v4.w)));
        mn = fminf(mn, fminf(fminf(v4.x, v4.y), fminf(v4.z, v4.w)));
    }
    for (int off = 32; off > 0; off >>= 1) {
        mx = fmaxf(mx, __shfl_down(mx, off));
        mn = fminf(mn, __shfl_down(mn, off));
    }
    __shared__ float smx[4], smn[4];
    int lid = threadIdx.x & 63, wid = threadIdx.x >> 6;
    if (lid == 0) { smx[wid] = mx; smn[wid] = mn; }
    __syncthreads();
    if (threadIdx.x == 0) {
        mx = fmaxf(fmaxf(smx[0], smx[1]), fmaxf(smx[2], smx[3]));
        mn = fminf(fminf(smn[0], smn[1]), fminf(smn[2], smn[3]));
        atomicMax(&mm[0], __float_as_uint(mx));
        atomicMin(&mm[1], __float_as_uint(mn));
    }
}

// ---------------------------------------------------------------------------
// Projection: dst = src @ W^T + b for three (src, W) pairs selected by
// blockIdx.y (q/k/v). M=1600 tiled 32 rows/block, N=128, K=128.
// Thread tile 4m x 4n; W staged in LDS in 64-wide K chunks (keeps static
// LDS < 64KB). Row pad 132/68 floats -> ~4-way-max bank aliasing on b128.
// ---------------------------------------------------------------------------
__global__ __launch_bounds__(256) void proj_kernel(
    const float* __restrict__ sq, const float* __restrict__ sk, const float* __restrict__ sv,
    const float* __restrict__ Wbase, const float* __restrict__ Bbase,
    float* __restrict__ q, float* __restrict__ k, float* __restrict__ v)
{
    int r = blockIdx.y;
    const float* src = (r == 0) ? sq : (r == 1 ? sk : sv);
    float* dst       = (r == 0) ? q  : (r == 1 ? k  : v);
    const float* Wm   = Wbase + r * DD * DD;
    const float* bias = Bbase + r * DD;
    int mbase = blockIdx.x * 32;
    __shared__ float sS[32][132];
    __shared__ float sWc[128][68];
    int t = threadIdx.x;

    for (int i = t; i < 32 * 32; i += 256) {
        int m = i >> 5, c = (i & 31) << 2;
        *(float4*)&sS[m][c] = *(const float4*)(src + (mbase + m) * DD + c);
    }
    __syncthreads();

    int nh = t & 31, mg = t >> 5;
    float acc[4][4] = {};
    for (int kb = 0; kb < 128; kb += 64) {
        for (int i = t; i < 128 * 16; i += 256) {
            int n = i >> 4, c = (i & 15) << 2;
            *(float4*)&sWc[n][c] = *(const float4*)(Wm + n * DD + kb + c);
        }
        __syncthreads();
#pragma unroll 4
        for (int kk = 0; kk < 64; kk += 4) {
            float4 a[4], w[4];
#pragma unroll
            for (int i2 = 0; i2 < 4; i2++) a[i2] = *(const float4*)&sS[mg * 4 + i2][kb + kk];
#pragma unroll
            for (int j = 0; j < 4; j++) w[j] = *(const float4*)&sWc[nh + 32 * j][kk];
#pragma unroll
            for (int i2 = 0; i2 < 4; i2++)
#pragma unroll
                for (int j = 0; j < 4; j++)
                    acc[i2][j] += a[i2].x * w[j].x + a[i2].y * w[j].y +
                                  a[i2].z * w[j].z + a[i2].w * w[j].w;
        }
        __syncthreads();
    }
#pragma unroll
    for (int i2 = 0; i2 < 4; i2++) {
        int m = mbase + mg * 4 + i2;
#pragma unroll
        for (int j = 0; j < 4; j++) {
            int n = nh + 32 * j;
            dst[m * DD + n] = acc[i2][j] + bias[n];
        }
    }
}

// ---------------------------------------------------------------------------
// mean_value[b,tau] = (1/128) * sum_s  q[b,(s+tau)%25,:] . k[b,s,:]
// One block per b; q,k rows staged in LDS; 25 block reductions (one sync).
// ---------------------------------------------------------------------------
__global__ __launch_bounds__(256) void corr_kernel(
    const float* __restrict__ q, const float* __restrict__ k, float* __restrict__ mv)
{
    int b = blockIdx.x;
    __shared__ float sq[LL * DD], sk[LL * DD];
    __shared__ float rbuf[LL][4];
    int t = threadIdx.x;
    for (int i = t; i < 800; i += 256) {
        int c = i << 2;
        *(float4*)&sq[c] = *(const float4*)(q + b * LL * DD + c);
        *(float4*)&sk[c] = *(const float4*)(k + b * LL * DD + c);
    }
    __syncthreads();
    int lid = t & 63, wid = t >> 6;
    for (int tau = 0; tau < LL; tau++) {
        float s = 0.f;
        for (int e = t; e < LL * DD; e += 256) {
            int srow = e >> 7, d = e & 127;
            int qrow = srow + tau; if (qrow >= LL) qrow -= LL;
            s += sq[qrow * DD + d] * sk[e];
        }
        for (int off = 32; off > 0; off >>= 1) s += __shfl_down(s, off);
        if (lid == 0) rbuf[tau][wid] = s;
    }
    __syncthreads();
    if (t < LL)
        mv[b * LL + t] = (rbuf[t][0] + rbuf[t][1] + rbuf[t][2] + rbuf[t][3]) * (1.0f / 128.0f);
}

// ---------------------------------------------------------------------------
// Batch-mean over b, top-3 shifts (permutation-invariant downstream, so any
// order ok), per-b softmax over the 3 gathered weights.
// ---------------------------------------------------------------------------
__global__ void topsm_kernel(const float* __restrict__ mv, float* __restrict__ tc,
                             int* __restrict__ idxout)
{
    __shared__ float sbm[LL];
    __shared__ int sidx[3];
    int t = threadIdx.x;
    if (t < LL) {
        float s = 0.f;
        for (int b = 0; b < BB; b++) s += mv[b * LL + t];
        sbm[t] = s;
    }
    __syncthreads();
    if (t == 0) {
        float loc[LL];
        for (int i = 0; i < LL; i++) loc[i] = sbm[i];
        for (int j = 0; j < 3; j++) {
            int bi = 0; float bvv = loc[0];
            for (int i = 1; i < LL; i++) if (loc[i] > bvv) { bvv = loc[i]; bi = i; }
            sidx[j] = bi; idxout[j] = bi; loc[bi] = -1e30f;
        }
    }
    __syncthreads();
    if (t < BB) {
        float w0 = mv[t * LL + sidx[0]];
        float w1 = mv[t * LL + sidx[1]];
        float w2 = mv[t * LL + sidx[2]];
        float m = fmaxf(w0, fmaxf(w1, w2));
        float e0 = expf(w0 - m), e1 = expf(w1 - m), e2 = expf(w2 - m);
        float inv = 1.0f / (e0 + e1 + e2);
        tc[t * 4 + 0] = e0 * inv; tc[t * 4 + 1] = e1 * inv; tc[t * 4 + 2] = e2 * inv;
    }
}

// ---------------------------------------------------------------------------
// agg[b,l,:] = sum_j tc[b,j] * v[b,(l+idx_j)%25,:]   then  dst = agg @ W3^T + b3
// Same GEMM structure as proj_kernel with the agg tile built on the fly.
// ---------------------------------------------------------------------------
__global__ __launch_bounds__(256) void aggproj_kernel(
    const float* __restrict__ v, const float* __restrict__ tc, const int* __restrict__ idx3,
    const float* __restrict__ Wm, const float* __restrict__ bias, float* __restrict__ dst)
{
    int mbase = blockIdx.x * 32;
    __shared__ float sS[32][132];
    __shared__ float sWc[128][68];
    int t = threadIdx.x;
    int i0 = idx3[0], i1 = idx3[1], i2x = idx3[2];

    for (int i = t; i < 32 * 32; i += 256) {
        int m = i >> 5, c = (i & 31) << 2;
        int row = mbase + m;
        int b = row / LL, l = row - b * LL;
        int l0 = l + i0;  if (l0 >= LL) l0 -= LL;
        int l1 = l + i1;  if (l1 >= LL) l1 -= LL;
        int l2 = l + i2x; if (l2 >= LL) l2 -= LL;
        float w0 = tc[b * 4 + 0], w1 = tc[b * 4 + 1], w2 = tc[b * 4 + 2];
        float4 v0 = *(const float4*)(v + (b * LL + l0) * DD + c);
        float4 v1 = *(const float4*)(v + (b * LL + l1) * DD + c);
        float4 v2 = *(const float4*)(v + (b * LL + l2) * DD + c);
        float4 a;
        a.x = w0 * v0.x + w1 * v1.x + w2 * v2.x;
        a.y = w0 * v0.y + w1 * v1.y + w2 * v2.y;
        a.z = w0 * v0.z + w1 * v1.z + w2 * v2.z;
        a.w = w0 * v0.w + w1 * v1.w + w2 * v2.w;
        *(float4*)&sS[m][c] = a;
    }
    __syncthreads();

    int nh = t & 31, mg = t >> 5;
    float acc[4][4] = {};
    for (int kb = 0; kb < 128; kb += 64) {
        for (int i = t; i < 128 * 16; i += 256) {
            int n = i >> 4, c = (i & 15) << 2;
            *(float4*)&sWc[n][c] = *(const float4*)(Wm + n * DD + kb + c);
        }
        __syncthreads();
#pragma unroll 4
        for (int kk = 0; kk < 64; kk += 4) {
            float4 a[4], w[4];
#pragma unroll
            for (int ii = 0; ii < 4; ii++) a[ii] = *(const float4*)&sS[mg * 4 + ii][kb + kk];
#pragma unroll
            for (int j = 0; j < 4; j++) w[j] = *(const float4*)&sWc[nh + 32 * j][kk];
#pragma unroll
            for (int ii = 0; ii < 4; ii++)
#pragma unroll
                for (int j = 0; j < 4; j++)
                    acc[ii][j] += a[ii].x * w[j].x + a[ii].y * w[j].y +
                                  a[ii].z * w[j].z + a[ii].w * w[j].w;
        }
        __syncthreads();
    }
#pragma unroll
    for (int ii = 0; ii < 4; ii++) {
        int m = mbase + mg * 4 + ii;
#pragma unroll
        for (int j = 0; j < 4; j++) {
            int n = nh + 32 * j;
            dst[m * DD + n] = acc[ii][j] + bias[n];
        }
    }
}

// ---------------------------------------------------------------------------
// pre_cat[b,c] = cat_emb[c] . (sum_l vw[l]*outc[b,l,:]) + vb
// ---------------------------------------------------------------------------
__global__ __launch_bounds__(256) void precat_kernel(
    const float* __restrict__ outc, const float* __restrict__ cat_emb,
    const float* __restrict__ vw, const float* __restrict__ vbp, float* __restrict__ dstc)
{
    int b = blockIdx.x, t = threadIdx.x;
    __shared__ float y[DD];
    __shared__ float svw[LL];
    if (t < LL) svw[t] = vw[t];
    __syncthreads();
    if (t < DD) {
        float s = 0.f;
        for (int l = 0; l < LL; l++) s += svw[l] * outc[(b * LL + l) * DD + t];
        y[t] = s;
    }
    __syncthreads();
    float vb = vbp[0];
    for (int c = t; c < CAT_N; c += 256) {
        float s = 0.f;
        for (int d = 0; d < DD; d += 4) {
            float4 ce4 = *(const float4*)(cat_emb + c * DD + d);
            s += ce4.x * y[d] + ce4.y * y[d + 1] + ce4.z * y[d + 2] + ce4.w * y[d + 3];
        }
        dstc[b * CAT_N + c] = s + vb;
    }
}

// ---------------------------------------------------------------------------
// pre_poi[b,p] = vb + sum_l vw[l] * exp(-D[poi[b,l],p]/(gmax-gmin))
//                                 * (poi_emb[p] . out[b,l,:])
// One block per (b, 128-p tile). Phase A: S[l][p] dots via register-tiled
// f32 GEMM with poi_emb staged in 64-wide K chunks. Phase B: coalesced D
// stream + exp + weighted reduce over l (split over 2 thread halves).
// ---------------------------------------------------------------------------
__global__ __launch_bounds__(256) void prepoi_kernel(
    const float* __restrict__ outp, const float* __restrict__ poi_emb,
    const int* __restrict__ poi_idx, const float* __restrict__ Dm,
    const unsigned* __restrict__ mm, const float* __restrict__ vw,
    const float* __restrict__ vbp, float* __restrict__ dstp)
{
    int b = blockIdx.y;
    int pbase = blockIdx.x << 7;
    __shared__ float sO[LL][132];
    __shared__ float sPc[128][68];
    __shared__ float sS[LL][132];
    __shared__ float svw[LL];
    __shared__ int srow[LL];
    __shared__ float red[128];
    int t = threadIdx.x;

    for (int i = t; i < 800; i += 256) {
        int l = i >> 5, c = (i & 31) << 2;
        *(float4*)&sO[l][c] = *(const float4*)(outp + (b * LL + l) * DD + c);
    }
    if (t < LL) { svw[t] = vw[t]; srow[t] = poi_idx[b * LL + t]; }
    __syncthreads();

    int nh = t & 31, mg = t >> 5;
    // thread covers p = pbase + nh + 32j (j=0..3), l in {mg, mg+8, mg+16} (+ l=24 for mg==0)
    float acc[4][4] = {};
    for (int kb = 0; kb < 128; kb += 64) {
        for (int i = t; i < 128 * 16; i += 256) {
            int p = i >> 4, c = (i & 15) << 2;
            float4 val = {0.f, 0.f, 0.f, 0.f};
            if (pbase + p < POI_N) val = *(const float4*)(poi_emb + (pbase + p) * DD + kb + c);
            *(float4*)&sPc[p][c] = val;
        }
        __syncthreads();
#pragma unroll 4
        for (int kk = 0; kk < 64; kk += 4) {
            float4 a0 = *(const float4*)&sO[mg][kb + kk];
            float4 a1 = *(const float4*)&sO[mg + 8][kb + kk];
            float4 a2 = *(const float4*)&sO[mg + 16][kb + kk];
            float4 a3 = {0.f, 0.f, 0.f, 0.f};
            if (mg == 0) a3 = *(const float4*)&sO[24][kb + kk];
#pragma unroll
            for (int j = 0; j < 4; j++) {
                float4 p4 = *(const float4*)&sPc[nh + 32 * j][kk];
                acc[j][0] += p4.x * a0.x + p4.y * a0.y + p4.z * a0.z + p4.w * a0.w;
                acc[j][1] += p4.x * a1.x + p4.y * a1.y + p4.z * a1.z + p4.w * a1.w;
                acc[j][2] += p4.x * a2.x + p4.y * a2.y + p4.z * a2.z + p4.w * a2.w;
                acc[j][3] += p4.x * a3.x + p4.y * a3.y + p4.z * a3.z + p4.w * a3.w;
            }
        }
        __syncthreads();
    }
#pragma unroll
    for (int j = 0; j < 4; j++) {
        int pl = nh + 32 * j;
        sS[mg][pl]      = acc[j][0];
        sS[mg + 8][pl]  = acc[j][1];
        sS[mg + 16][pl] = acc[j][2];
        if (mg == 0) sS[24][pl] = acc[j][3];
    }
    __syncthreads();

    float gmax = __uint_as_float(mm[0]);
    float gmin = __uint_as_float(mm[1]);
    float ninv = -1.0f / (gmax - gmin);
    int pp = t & 127, half = t >> 7;
    int p = pbase + pp;
    float s = 0.f;
    if (p < POI_N) {
        int l0 = half ? 13 : 0, l1 = half ? 25 : 13;
        for (int l = l0; l < l1; l++) {
            float dv = Dm[(size_t)srow[l] * POI_N + p];
            s += svw[l] * expf(dv * ninv) * sS[l][pp];
        }
    }
    if (half) red[pp] = s;
    __syncthreads();
    if (!half && p < POI_N)
        dstp[(size_t)b * POI_N + p] = s + red[pp] + vbp[0];
}

// ---------------------------------------------------------------------------
extern "C" void kernel_launch(void* const* d_in, const int* in_sizes, int n_in,
                              void* d_out, int out_size, void* d_ws, size_t ws_size,
                              hipStream_t stream)
{
    const int*   user = (const int*)d_in[0];
    const int*   poi  = (const int*)d_in[1];
    const int*   cat  = (const int*)d_in[2];
    const int*   tod  = (const int*)d_in[5];
    const int*   dow  = (const int*)d_in[6];
    const float* ue   = (const float*)d_in[8];
    const float* pe   = (const float*)d_in[9];
    const float* ce   = (const float*)d_in[10];
    const float* te   = (const float*)d_in[11];
    const float* de   = (const float*)d_in[12];
    const float* uec  = (const float*)d_in[13];
    const float* tec  = (const float*)d_in[14];
    const float* dec  = (const float*)d_in[15];
    const float* W    = (const float*)d_in[16];
    const float* Bv   = (const float*)d_in[17];
    const float* vw   = (const float*)d_in[18];
    const float* vb   = (const float*)d_in[19];
    const float* Dm   = (const float*)d_in[20];

    float* ws = (float*)d_ws;
    float* O0 = ws;
    float* C0 = ws + 204800;
    float* O1 = ws + 409600;
    float* C1 = ws + 614400;
    float* Q  = ws + 819200;
    float* Kb = ws + 1024000;
    float* V  = ws + 1228800;
    float* MV = ws + 1433600;                  // 1600
    float* TC = ws + 1435200;                  // 256
    int*   IDX = (int*)(ws + 1435456);         // 3
    unsigned* MM = (unsigned*)(ws + 1435460);  // 2

    float* out_poi = (float*)d_out;
    float* out_cat = out_poi + BB * POI_N;

    embed_kernel<<<800, 256, 0, stream>>>(user, poi, cat, tod, dow,
                                          ue, pe, ce, te, de, uec, tec, dec, O0, C0, MM);
    minmax_kernel<<<BL, 256, 0, stream>>>(poi, Dm, MM);

    auto ac = [&](const float* qx, const float* kx, const float* vx, int i, int j, float* dstbuf) {
        const float* Wb = W + (size_t)((i * 4 + j) * 4) * DD * DD;
        const float* Bb = Bv + (size_t)((i * 4 + j) * 4) * DD;
        proj_kernel<<<dim3(50, 3), 256, 0, stream>>>(qx, kx, vx, Wb, Bb, Q, Kb, V);
        corr_kernel<<<BB, 256, 0, stream>>>(Q, Kb, MV);
        topsm_kernel<<<1, 256, 0, stream>>>(MV, TC, IDX);
        aggproj_kernel<<<50, 256, 0, stream>>>(V, TC, IDX, Wb + 3 * DD * DD, Bb + 3 * DD, dstbuf);
    };

    // layer 0
    ac(O0, O0, O0, 0, 0, O1);   // out  = ac(out,out,out)
    ac(C0, C0, C0, 0, 1, C1);   // outc = ac(outc,outc,outc)
    ac(O1, C1, C1, 0, 2, O0);   // out  = ac(out,outc,outc)
    ac(C1, O0, O0, 0, 3, C0);   // outc = ac(outc,out,out)
    // layer 1
    ac(O0, O0, O0, 1, 0, O1);
    ac(C0, C0, C0, 1, 1, C1);
    ac(O1, C1, C1, 1, 2, O0);
    ac(C1, O0, O0, 1, 3, C0);

    precat_kernel<<<BB, 256, 0, stream>>>(C0, ce, vw, vb, out_cat);
    prepoi_kernel<<<dim3(79, BB), 256, 0, stream>>>(O0, pe, poi, Dm, MM, vw, vb, out_poi);
}